// Round 6
// baseline (220.350 us; speedup 1.0000x reference)
//
#include <hip/hip_runtime.h>
#include <hip/hip_bf16.h>

typedef unsigned int  uint32;
typedef __attribute__((ext_vector_type(8))) short short8;   // 8 bf16 (4 VGPR)
typedef __attribute__((ext_vector_type(4))) float f32x4;

#define NNODES   50000
#define IN_DIM   256
#define OUT_DIM  64
#define SUPPORT  8
#define NUM_BASES 4
#define NNZ      800000

#define M_PAD    50048          // 391 * 128
#define NBIG     512            // SUPPORT * OUT_DIM
#define CAP      48             // bucket cap/row (Poisson(16): E[max]~35, P(>48)~1e-6)

#define GEMM_BLOCKS 1564        // 391 * 4
#define FILL_BLOCKS 512
#define MEGA_BLOCKS 2076        // 2048 interleaved (3:1) + 28 gemm tail
#define CAST_BLOCKS 6256        // M_PAD*IN_DIM/8/256
#define CW_BLOCKS   (CAST_BLOCKS + NBIG)

// ---- workspace layout (bytes) ---------------------------------------------
#define EBF_OFF  0u                        // bf16 [50048][256]   25,624,576 B
#define WT_OFF   25624576u                 // bf16 [512][256]        262,144 B
#define FW_OFF   25886720u                 // bf16 [400000][64]   51,200,000 B
#define CNT_OFF  77086720u                 // int  [50000]           200,000 B
#define BK_OFF   77286720u                 // int2 [50000][48]    19,200,000 B -> 96.5 MB

__device__ __forceinline__ unsigned short f2bf_rne(float f) {
    uint32 u = __float_as_uint(f);
    u = (u + 0x7fffu + ((u >> 16) & 1u)) >> 16;
    return (unsigned short)u;
}
__device__ __forceinline__ float bf2f(unsigned short b) {
    return __uint_as_float(((uint32)b) << 16);
}
__device__ __forceinline__ void load_lds16(const void* g, void* l) {
    __builtin_amdgcn_global_load_lds(
        (const __attribute__((address_space(1))) void*)g,
        (__attribute__((address_space(3))) void*)l, 16, 0, 0);
}

// ---------------------------------------------------------------------------
// K1: heterogeneous cast(E fp32->bf16, zero-pad) + build WbigT
// ---------------------------------------------------------------------------
__global__ __launch_bounds__(256) void cast_wbig_kernel(
    const float* __restrict__ E, unsigned short* __restrict__ Ebf,
    const float* __restrict__ WF, const float* __restrict__ comp,
    unsigned short* __restrict__ WT)
{
    const int bid = blockIdx.x;
    const int tid = threadIdx.x;

    if (bid >= CAST_BLOCKS) {
        // WbigT[n][k] = sum_b comp[s,b] * WF[b][k][o],  n = s*64+o (k-major)
        const int n = bid - CAST_BLOCKS;     // 0..511
        const int k = tid;                   // 0..255
        const int o = n & 63, s = n >> 6;
        float v = 0.f;
        #pragma unroll
        for (int b = 0; b < NUM_BASES; ++b)
            v = fmaf(comp[s * 4 + b], WF[(b * IN_DIM + k) * OUT_DIM + o], v);
        WT[n * IN_DIM + k] = f2bf_rne(v);
        return;
    }

    const int i8 = bid * 256 + tid;          // group of 8 elems
    unsigned short o[8];
    if (i8 < NNODES * IN_DIM / 8) {
        const float4 f0 = reinterpret_cast<const float4*>(E)[i8 * 2];
        const float4 f1 = reinterpret_cast<const float4*>(E)[i8 * 2 + 1];
        o[0]=f2bf_rne(f0.x); o[1]=f2bf_rne(f0.y); o[2]=f2bf_rne(f0.z); o[3]=f2bf_rne(f0.w);
        o[4]=f2bf_rne(f1.x); o[5]=f2bf_rne(f1.y); o[6]=f2bf_rne(f1.z); o[7]=f2bf_rne(f1.w);
    } else {
        #pragma unroll
        for (int j = 0; j < 8; ++j) o[j] = 0;
    }
    reinterpret_cast<ulonglong2*>(Ebf)[i8] = *reinterpret_cast<ulonglong2*>(o);
}

// ---------------------------------------------------------------------------
// K2: MEGA = MFMA GEMM tiles + interleaved bucket-fill blocks.
// bid in [0,2048): (bid&3)==3 -> fill block (bid>>2), else gemm 3*(bid>>2)+(bid&3)
// bid in [2048,2076): gemm 1536 + (bid-2048).
// GEMM math identical to validated round-4/5 kernel (absmax 0.125).
// ---------------------------------------------------------------------------
__global__ __launch_bounds__(256) void mega_kernel(
    const unsigned short* __restrict__ Ebf,
    const unsigned short* __restrict__ WT,
    unsigned short* __restrict__ FW,
    const float* __restrict__ vals, const int* __restrict__ rows,
    const int* __restrict__ cols, int* __restrict__ cnt,
    int2* __restrict__ bucket)
{
    __shared__ short Alds[128 * 64];
    __shared__ short Blds[128 * 64];

    const int bid = blockIdx.x;
    const int tid = threadIdx.x;

    int g;
    if (bid < 2048) {
        if ((bid & 3) == 3) {
            // ---------------- fill block: grid-stride over edges ----------
            for (int e = (bid >> 2) * 256 + tid; e < NNZ; e += FILL_BLOCKS * 256) {
                const int r = rows[e];
                const int p = atomicAdd(&cnt[r], 1);
                if (p < CAP)
                    bucket[(size_t)r * CAP + p] =
                        make_int2(cols[e], __float_as_int(vals[e]));
            }
            return;
        }
        g = 3 * (bid >> 2) + (bid & 3);
    } else {
        g = 1536 + (bid - 2048);
    }

    // ---------------- gemm block g ----------------
    const int lane = tid & 63;
    const int wid  = tid >> 6;          // 0..3
    const int wr   = wid >> 1;          // wave row quadrant
    const int wc   = wid & 1;           // wave col quadrant
    const int m0   = (g % 391) * 128;
    const int n0   = (g / 391) * 128;

    f32x4 acc[4][4];
    #pragma unroll
    for (int i = 0; i < 4; ++i)
        #pragma unroll
        for (int j = 0; j < 4; ++j) acc[i][j] = (f32x4){0.f, 0.f, 0.f, 0.f};

    const int srow = lane >> 3;          // 0..7  (row within 8-row chunk)
    const int scol = (lane & 7) * 16;    // byte offset within 128B row

    for (int kt = 0; kt < 4; ++kt) {
        #pragma unroll
        for (int i = 0; i < 4; ++i) {
            const int c   = wid * 4 + i;           // chunk 0..15
            const int row = c * 8 + srow;          // tile row 0..127
            load_lds16(
                (const char*)Ebf + (size_t)(m0 + row) * 512 + kt * 128 + scol,
                (char*)Alds + c * 1024);
            load_lds16(
                (const char*)WT + (size_t)(n0 + row) * 512 + kt * 128 + scol,
                (char*)Blds + c * 1024);
        }
        __syncthreads();

        #pragma unroll
        for (int ks = 0; ks < 2; ++ks) {
            short8 af[4], bf[4];
            const int k0 = ks * 32 + (lane >> 4) * 8;
            #pragma unroll
            for (int mi = 0; mi < 4; ++mi)
                af[mi] = *reinterpret_cast<const short8*>(
                    &Alds[(wr * 64 + mi * 16 + (lane & 15)) * 64 + k0]);
            #pragma unroll
            for (int ni = 0; ni < 4; ++ni)
                bf[ni] = *reinterpret_cast<const short8*>(
                    &Blds[(wc * 64 + ni * 16 + (lane & 15)) * 64 + k0]);
            #pragma unroll
            for (int mi = 0; mi < 4; ++mi)
                #pragma unroll
                for (int ni = 0; ni < 4; ++ni)
                    acc[mi][ni] = __builtin_amdgcn_mfma_f32_16x16x32_bf16(
                        af[mi], bf[ni], acc[mi][ni], 0, 0, 0);
        }
        __syncthreads();
    }

    // epilogue: C row = (lane>>4)*4 + reg, col = lane&15
    #pragma unroll
    for (int mi = 0; mi < 4; ++mi) {
        #pragma unroll
        for (int r = 0; r < 4; ++r) {
            const int row = m0 + wr * 64 + mi * 16 + (lane >> 4) * 4 + r;
            if (row < NNODES) {
                #pragma unroll
                for (int ni = 0; ni < 4; ++ni) {
                    const int col = n0 + wc * 64 + ni * 16 + (lane & 15);
                    FW[((size_t)(col >> 6) * NNODES + row) * 64 + (col & 63)]
                        = f2bf_rne(acc[mi][ni][r]);
                }
            }
        }
    }
}

// ---------------------------------------------------------------------------
// K3: CSR scatter. One wave per row; lane = output column. Edge list loaded
// once (lane e holds edge slot e), broadcast via readlane; 4 accumulators.
// ---------------------------------------------------------------------------
__global__ __launch_bounds__(256) void scatter_csr_kernel(
    const int* __restrict__ cnt, const int2* __restrict__ bucket,
    const unsigned short* __restrict__ FW, const float* __restrict__ bias,
    float* __restrict__ out)
{
    const int lane = threadIdx.x & 63;
    const int r    = blockIdx.x * 4 + (threadIdx.x >> 6);
    if (r >= NNODES) return;

    const int n = min(cnt[r], CAP);
    int2 my = make_int2(0, 0);
    if (lane < CAP) my = bucket[(size_t)r * CAP + lane];

    float a0 = 0.f, a1 = 0.f, a2 = 0.f, a3 = 0.f;
    int j = 0;
    for (; j + 4 <= n; j += 4) {
        const uint32 c0 = (uint32)__builtin_amdgcn_readlane(my.x, j);
        const uint32 c1 = (uint32)__builtin_amdgcn_readlane(my.x, j + 1);
        const uint32 c2 = (uint32)__builtin_amdgcn_readlane(my.x, j + 2);
        const uint32 c3 = (uint32)__builtin_amdgcn_readlane(my.x, j + 3);
        const float  v0 = __int_as_float(__builtin_amdgcn_readlane(my.y, j));
        const float  v1 = __int_as_float(__builtin_amdgcn_readlane(my.y, j + 1));
        const float  v2 = __int_as_float(__builtin_amdgcn_readlane(my.y, j + 2));
        const float  v3 = __int_as_float(__builtin_amdgcn_readlane(my.y, j + 3));
        const unsigned short f0 = FW[(size_t)c0 * 64 + lane];
        const unsigned short f1 = FW[(size_t)c1 * 64 + lane];
        const unsigned short f2 = FW[(size_t)c2 * 64 + lane];
        const unsigned short f3 = FW[(size_t)c3 * 64 + lane];
        a0 = fmaf(v0, bf2f(f0), a0);
        a1 = fmaf(v1, bf2f(f1), a1);
        a2 = fmaf(v2, bf2f(f2), a2);
        a3 = fmaf(v3, bf2f(f3), a3);
    }
    for (; j < n; ++j) {
        const uint32 c = (uint32)__builtin_amdgcn_readlane(my.x, j);
        const float  v = __int_as_float(__builtin_amdgcn_readlane(my.y, j));
        a0 = fmaf(v, bf2f(FW[(size_t)c * 64 + lane]), a0);
    }
    const float acc = (a0 + a1) + (a2 + a3);
    out[(size_t)r * OUT_DIM + lane] = fmaxf(acc + bias[lane], 0.f);
}

extern "C" void kernel_launch(void* const* d_in, const int* in_sizes, int n_in,
                              void* d_out, int out_size, void* d_ws, size_t ws_size,
                              hipStream_t stream) {
    const float* E     = (const float*)d_in[0];
    const float* WF    = (const float*)d_in[1];
    const float* comp  = (const float*)d_in[2];
    const float* b     = (const float*)d_in[3];
    const float* Avals = (const float*)d_in[4];
    const int*   Arows = (const int*)d_in[5];
    const int*   Acols = (const int*)d_in[6];
    float* out = (float*)d_out;

    char* ws = (char*)d_ws;
    unsigned short* Ebf = (unsigned short*)(ws + EBF_OFF);
    unsigned short* WT  = (unsigned short*)(ws + WT_OFF);
    unsigned short* FW  = (unsigned short*)(ws + FW_OFF);
    int*   cnt    = (int*)(ws + CNT_OFF);
    int2*  bucket = (int2*)(ws + BK_OFF);

    hipMemsetAsync(cnt, 0, NNODES * sizeof(int), stream);

    cast_wbig_kernel<<<CW_BLOCKS, 256, 0, stream>>>(E, Ebf, WF, comp, WT);

    mega_kernel<<<MEGA_BLOCKS, 256, 0, stream>>>(
        Ebf, WT, FW, Avals, Arows, Acols, cnt, bucket);

    scatter_csr_kernel<<<(NNODES + 3) / 4, 256, 0, stream>>>(
        cnt, bucket, FW, b, out);
}

// Round 9
// 210.036 us; speedup vs baseline: 1.0491x; 1.0491x over previous
//
#include <hip/hip_runtime.h>
#include <hip/hip_bf16.h>

typedef unsigned int  uint32;
typedef __attribute__((ext_vector_type(8))) short short8;   // 8 bf16 (4 VGPR)
typedef __attribute__((ext_vector_type(4))) float f32x4;

#define NNODES   50000
#define IN_DIM   256
#define OUT_DIM  64
#define SUPPORT  8
#define NUM_BASES 4
#define NNZ      800000

#define M_PAD    50048          // 391 * 128
#define NBIG     512            // SUPPORT * OUT_DIM
#define CAST_BLOCKS 6256        // M_PAD*IN_DIM/8/256
#define CW_BLOCKS   (CAST_BLOCKS + NBIG)

// ---- binning geometry -----------------------------------------------------
#define NBINS    782            // ceil(50000/64); bin = row >> 6
#define P1_BLOCKS 128
#define EPB      6250           // NNZ / P1_BLOCKS (exact)
#define SEGCAP   32             // per (block,bin) cap; lambda=8, P(>=32)~1e-10
#define RAWCAP   1536           // per-bin total cap; lambda=1024, 16 sd

// ---- workspace layout (bytes) ---------------------------------------------
// binned ALIASES Ebf: bin_kernel runs after gemm consumed Ebf (stream order).
#define EBF_OFF  0u                        // bf16 [50048][256]   25,624,576 B
#define BIN_OFF  0u                        // int2 [128][782][32] 25,600,000 B
#define WT_OFF   25624576u                 // bf16 [512][256]        262,144 B
#define FW_OFF   25886720u                 // bf16 [400000][64]   51,200,000 B
#define BC_OFF   77086720u                 // int  [128*782]         400,384 B

__device__ __forceinline__ unsigned short f2bf_rne(float f) {
    uint32 u = __float_as_uint(f);
    u = (u + 0x7fffu + ((u >> 16) & 1u)) >> 16;
    return (unsigned short)u;
}
__device__ __forceinline__ float bf2f(unsigned short b) {
    return __uint_as_float(((uint32)b) << 16);
}
__device__ __forceinline__ void load_lds16(const void* g, void* l) {
    __builtin_amdgcn_global_load_lds(
        (const __attribute__((address_space(1))) void*)g,
        (__attribute__((address_space(3))) void*)l, 16, 0, 0);
}

// ---------------------------------------------------------------------------
// K1: heterogeneous cast(E fp32->bf16, zero-pad) + build WbigT  (validated r6)
// ---------------------------------------------------------------------------
__global__ __launch_bounds__(256) void cast_wbig_kernel(
    const float* __restrict__ E, unsigned short* __restrict__ Ebf,
    const float* __restrict__ WF, const float* __restrict__ comp,
    unsigned short* __restrict__ WT)
{
    const int bid = blockIdx.x;
    const int tid = threadIdx.x;

    if (bid >= CAST_BLOCKS) {
        const int n = bid - CAST_BLOCKS;     // 0..511
        const int k = tid;                   // 0..255
        const int o = n & 63, s = n >> 6;
        float v = 0.f;
        #pragma unroll
        for (int b = 0; b < NUM_BASES; ++b)
            v = fmaf(comp[s * 4 + b], WF[(b * IN_DIM + k) * OUT_DIM + o], v);
        WT[n * IN_DIM + k] = f2bf_rne(v);
        return;
    }

    const int i8 = bid * 256 + tid;          // group of 8 elems
    unsigned short o[8];
    if (i8 < NNODES * IN_DIM / 8) {
        const float4 f0 = reinterpret_cast<const float4*>(E)[i8 * 2];
        const float4 f1 = reinterpret_cast<const float4*>(E)[i8 * 2 + 1];
        o[0]=f2bf_rne(f0.x); o[1]=f2bf_rne(f0.y); o[2]=f2bf_rne(f0.z); o[3]=f2bf_rne(f0.w);
        o[4]=f2bf_rne(f1.x); o[5]=f2bf_rne(f1.y); o[6]=f2bf_rne(f1.z); o[7]=f2bf_rne(f1.w);
    } else {
        #pragma unroll
        for (int j = 0; j < 8; ++j) o[j] = 0;
    }
    reinterpret_cast<ulonglong2*>(Ebf)[i8] = *reinterpret_cast<ulonglong2*>(o);
}

// ---------------------------------------------------------------------------
// K2: MFMA GEMM (validated math, r4-r6) + XOR-swizzled LDS (T2).
// LDS stays linear for global_load_lds; the SOURCE 16B-slot is pre-swizzled
// (slot ^= row&7) and reads apply the same involution -> banks spread 4->32.
// ---------------------------------------------------------------------------
__global__ __launch_bounds__(256) void gemm_kernel(
    const unsigned short* __restrict__ Ebf,
    const unsigned short* __restrict__ WT,
    unsigned short* __restrict__ FW)
{
    __shared__ short Alds[128 * 64];
    __shared__ short Blds[128 * 64];

    const int tid  = threadIdx.x;
    const int lane = tid & 63;
    const int wid  = tid >> 6;          // 0..3
    const int wr   = wid >> 1;          // wave row quadrant
    const int wc   = wid & 1;           // wave col quadrant
    const int m0   = blockIdx.x * 128;
    const int n0   = blockIdx.y * 128;

    f32x4 acc[4][4];
    #pragma unroll
    for (int i = 0; i < 4; ++i)
        #pragma unroll
        for (int j = 0; j < 4; ++j) acc[i][j] = (f32x4){0.f, 0.f, 0.f, 0.f};

    const int srow    = lane >> 3;                    // row within 8-row chunk
    const int scol_sw = ((lane & 7) ^ srow) << 4;     // swizzled source byte-col

    for (int kt = 0; kt < 4; ++kt) {
        #pragma unroll
        for (int i = 0; i < 4; ++i) {
            const int c   = wid * 4 + i;           // chunk 0..15
            const int row = c * 8 + srow;          // tile row 0..127
            load_lds16(
                (const char*)Ebf + (size_t)(m0 + row) * 512 + kt * 128 + scol_sw,
                (char*)Alds + c * 1024);
            load_lds16(
                (const char*)WT + (size_t)(n0 + row) * 512 + kt * 128 + scol_sw,
                (char*)Blds + c * 1024);
        }
        __syncthreads();

        #pragma unroll
        for (int ks = 0; ks < 2; ++ks) {
            short8 af[4], bf[4];
            // swizzled short-offset: slot = (k0>>3) ^ (row&7); row&7 == lane&7
            const int sa = (((ks * 4 + (lane >> 4)) ^ (lane & 7)) << 3);
            #pragma unroll
            for (int mi = 0; mi < 4; ++mi)
                af[mi] = *reinterpret_cast<const short8*>(
                    &Alds[(wr * 64 + mi * 16 + (lane & 15)) * 64 + sa]);
            #pragma unroll
            for (int ni = 0; ni < 4; ++ni)
                bf[ni] = *reinterpret_cast<const short8*>(
                    &Blds[(wc * 64 + ni * 16 + (lane & 15)) * 64 + sa]);
            #pragma unroll
            for (int mi = 0; mi < 4; ++mi)
                #pragma unroll
                for (int ni = 0; ni < 4; ++ni)
                    acc[mi][ni] = __builtin_amdgcn_mfma_f32_16x16x32_bf16(
                        af[mi], bf[ni], acc[mi][ni], 0, 0, 0);
        }
        __syncthreads();
    }

    // epilogue (validated): C row = (lane>>4)*4 + reg, col = lane&15
    #pragma unroll
    for (int mi = 0; mi < 4; ++mi) {
        #pragma unroll
        for (int r = 0; r < 4; ++r) {
            const int row = m0 + wr * 64 + mi * 16 + (lane >> 4) * 4 + r;
            if (row < NNODES) {
                #pragma unroll
                for (int ni = 0; ni < 4; ++ni) {
                    const int col = n0 + wc * 64 + ni * 16 + (lane & 15);
                    FW[((size_t)(col >> 6) * NNODES + row) * 64 + (col & 63)]
                        = f2bf_rne(acc[mi][ni][r]);
                }
            }
        }
    }
}

// ---------------------------------------------------------------------------
// K3: phase-1 bin. Zero global atomics. Block bid owns edges
// [bid*EPB, (bid+1)*EPB); bins by row>>6 via LDS cursors into its own
// contiguous [NBINS][SEGCAP] window (200KB -> L2-coalesced writebacks).
// Entry: x = (row&63)<<19 | col (col<2^19), y = val bits.
// ---------------------------------------------------------------------------
__global__ __launch_bounds__(256) void bin_kernel(
    const float* __restrict__ vals, const int* __restrict__ rows,
    const int* __restrict__ cols, int* __restrict__ bcnt,
    int2* __restrict__ binned)
{
    __shared__ int cur[NBINS];
    const int tid = threadIdx.x, bid = blockIdx.x;
    for (int i = tid; i < NBINS; i += 256) cur[i] = 0;
    __syncthreads();

    const int base = bid * EPB;
    for (int i = tid; i < EPB; i += 256) {
        const int e = base + i;
        const int r = rows[e];
        const int c = cols[e];
        const int v = __float_as_int(vals[e]);
        const int b = r >> 6;
        const int p = atomicAdd(&cur[b], 1);     // LDS atomic
        if (p < SEGCAP)
            binned[(size_t)(bid * NBINS + b) * SEGCAP + p] =
                make_int2(((r & 63) << 19) | c, v);
    }
    __syncthreads();
    for (int i = tid; i < NBINS; i += 256)
        bcnt[bid * NBINS + i] = min(cur[i], SEGCAP);
}

// ---------------------------------------------------------------------------
// K4: phase-2 fused bin-scatter. One block per 64-row bin: gather the bin's
// ~1024 edges from the 128 segments, counting-sort by row IN LDS, then each
// wave reduces its rows (edges broadcast from LDS; FW gathered from L3),
// fused with bias+relu. No global bucket, no memset.
// ---------------------------------------------------------------------------
__global__ __launch_bounds__(256) void bin_scatter_kernel(
    const int* __restrict__ bcnt, const int2* __restrict__ binned,
    const unsigned short* __restrict__ FW, const float* __restrict__ bias,
    float* __restrict__ out)
{
    __shared__ int2 raw[RAWCAP];
    __shared__ int2 srt[RAWCAP];
    __shared__ int  sscan[P1_BLOCKS];
    __shared__ int  seg_off[P1_BLOCKS + 1];
    __shared__ int  hscan[64];
    __shared__ int  row_off[65];
    __shared__ int  cur[64];

    const int tid  = threadIdx.x;
    const int beta = blockIdx.x;                 // bin id

    // 1) segment counts -> inclusive scan -> seg_off
    if (tid < P1_BLOCKS) sscan[tid] = bcnt[tid * NBINS + beta];
    __syncthreads();
    for (int off = 1; off < P1_BLOCKS; off <<= 1) {
        int v = 0;
        if (tid < P1_BLOCKS && tid >= off) v = sscan[tid - off];
        __syncthreads();
        if (tid < P1_BLOCKS) sscan[tid] += v;
        __syncthreads();
    }
    if (tid < P1_BLOCKS) seg_off[tid + 1] = sscan[tid];
    if (tid == 0) seg_off[0] = 0;
    __syncthreads();
    const int T = min(seg_off[P1_BLOCKS], RAWCAP);

    // 2) gather segments into raw[] (binary search segment per entry)
    for (int i = tid; i < T; i += 256) {
        int lo = 0, hi = P1_BLOCKS - 1;
        while (lo < hi) {
            const int mid = (lo + hi + 1) >> 1;
            if (seg_off[mid] <= i) lo = mid; else hi = mid - 1;
        }
        raw[i] = binned[(size_t)(lo * NBINS + beta) * SEGCAP + (i - seg_off[lo])];
    }
    // 3) histogram by row_local
    if (tid < 64) hscan[tid] = 0;
    __syncthreads();
    for (int i = tid; i < T; i += 256)
        atomicAdd(&hscan[raw[i].x >> 19], 1);
    __syncthreads();
    // inclusive scan of 64
    for (int off = 1; off < 64; off <<= 1) {
        int v = 0;
        if (tid < 64 && tid >= off) v = hscan[tid - off];
        __syncthreads();
        if (tid < 64) hscan[tid] += v;
        __syncthreads();
    }
    if (tid < 64) row_off[tid + 1] = hscan[tid];
    if (tid == 0) row_off[0] = 0;
    __syncthreads();
    if (tid < 64) cur[tid] = row_off[tid];
    __syncthreads();
    // 4) place into row-sorted order
    for (int i = tid; i < T; i += 256) {
        const int rl = raw[i].x >> 19;
        const int p  = atomicAdd(&cur[rl], 1);
        srt[p] = make_int2(raw[i].x & 0x7FFFF, raw[i].y);
    }
    __syncthreads();

    // 5) compute: wave w handles rows w, w+4, ... ; lane = output column
    const int lane = tid & 63;
    const int w    = tid >> 6;
    const float bl = bias[lane];
    for (int rl = w; rl < 64; rl += 4) {
        const int r = (beta << 6) + rl;
        if (r >= NNODES) break;
        const int lo = row_off[rl];
        const int n  = row_off[rl + 1] - lo;
        float a0 = 0.f, a1 = 0.f, a2 = 0.f, a3 = 0.f;
        int j = 0;
        for (; j + 4 <= n; j += 4) {
            const int2 e0 = srt[lo + j];
            const int2 e1 = srt[lo + j + 1];
            const int2 e2 = srt[lo + j + 2];
            const int2 e3 = srt[lo + j + 3];
            const unsigned short f0 = FW[(size_t)e0.x * 64 + lane];
            const unsigned short f1 = FW[(size_t)e1.x * 64 + lane];
            const unsigned short f2 = FW[(size_t)e2.x * 64 + lane];
            const unsigned short f3 = FW[(size_t)e3.x * 64 + lane];
            a0 = fmaf(__int_as_float(e0.y), bf2f(f0), a0);
            a1 = fmaf(__int_as_float(e1.y), bf2f(f1), a1);
            a2 = fmaf(__int_as_float(e2.y), bf2f(f2), a2);
            a3 = fmaf(__int_as_float(e3.y), bf2f(f3), a3);
        }
        for (; j < n; ++j) {
            const int2 e = srt[lo + j];
            a0 = fmaf(__int_as_float(e.y), bf2f(FW[(size_t)e.x * 64 + lane]), a0);
        }
        const float acc = (a0 + a1) + (a2 + a3);
        out[(size_t)r * OUT_DIM + lane] = fmaxf(acc + bl, 0.f);
    }
}

extern "C" void kernel_launch(void* const* d_in, const int* in_sizes, int n_in,
                              void* d_out, int out_size, void* d_ws, size_t ws_size,
                              hipStream_t stream) {
    const float* E     = (const float*)d_in[0];
    const float* WF    = (const float*)d_in[1];
    const float* comp  = (const float*)d_in[2];
    const float* b     = (const float*)d_in[3];
    const float* Avals = (const float*)d_in[4];
    const int*   Arows = (const int*)d_in[5];
    const int*   Acols = (const int*)d_in[6];
    float* out = (float*)d_out;

    char* ws = (char*)d_ws;
    unsigned short* Ebf    = (unsigned short*)(ws + EBF_OFF);
    unsigned short* WT     = (unsigned short*)(ws + WT_OFF);
    unsigned short* FW     = (unsigned short*)(ws + FW_OFF);
    int*            bcnt   = (int*)(ws + BC_OFF);
    int2*           binned = (int2*)(ws + BIN_OFF);  // aliases Ebf (post-gemm)

    cast_wbig_kernel<<<CW_BLOCKS, 256, 0, stream>>>(E, Ebf, WF, comp, WT);

    gemm_kernel<<<dim3(M_PAD / 128, NBIG / 128), 256, 0, stream>>>(Ebf, WT, FW);

    bin_kernel<<<P1_BLOCKS, 256, 0, stream>>>(Avals, Arows, Acols, bcnt, binned);

    bin_scatter_kernel<<<NBINS, 256, 0, stream>>>(bcnt, binned, FW, b, out);
}